// Round 4
// baseline (579.375 us; speedup 1.0000x reference)
//
#include <hip/hip_runtime.h>
#include <cstdint>
#include <cstddef>

#define BB 4
#define NN 4096
#define DD 768
#define EE 2304      // 3*DD
#define MTOT 16384   // BB*NN
static constexpr float ATT_SCALE = 0.03608439182435161f;  // 1/sqrt(768)

typedef _Float16 v8h __attribute__((ext_vector_type(8)));
typedef _Float16 v4h __attribute__((ext_vector_type(4)));
typedef float v4f __attribute__((ext_vector_type(4)));

// Async global->LDS, 16B per lane. LDS dest = wave-uniform base + lane*16.
__device__ __forceinline__ void async_copy16(void* lds, const void* gmem) {
  __builtin_amdgcn_global_load_lds(
      (const __attribute__((address_space(1))) uint32_t*)(uintptr_t)gmem,
      (__attribute__((address_space(3))) uint32_t*)(uintptr_t)lds,
      16, 0, 0);
}

#define VM_WAIT(n) asm volatile("s_waitcnt vmcnt(" #n ")" ::: "memory")
#define LGKM0 asm volatile("s_waitcnt lgkmcnt(0)" ::: "memory")
#define SCHED0 __builtin_amdgcn_sched_barrier(0)
#define BAR __builtin_amdgcn_s_barrier()

enum { EPI_QKV = 0, EPI_F16 = 1, EPI_OUT = 2, EPI_PV = 3 };

// ---------------------------------------------------------------------------
// gemm128: C[M,N] = A[M,K] @ Bt[N,K]^T.  128x128 tile, BK=64, 256 threads =
// 4 waves 2x2, 4x4 16x16x32 MFMA per wave.  Simple 2-barrier K-loop (m97
// structure): with 3 co-resident blocks/CU the cross-block wave overlap hides
// the barrier drain (m114) — proven in round 0 of this session.
//
// OCCUPANCY PIN (the round-4 change): LDS padded 32->44 KB so exactly
// floor(160/44) = 3 blocks/CU are co-resident (VGPR=80 would otherwise allow
// 4).  768 co-resident blocks chip-wide makes the grids below EXACT:
//   QKV 128x18 = 2304 = 3.0 rounds (zero drain tail)
//   PV  32x6x4 =  768 = 1.0 round
//   OUT 128x6  =  768 = 1.0 round
// This removes the 18-25% wave-quantization idle measured in rounds 0-3.
//
// LDS layout: row-major 128x64 with XOR chunk swizzle — row r's 16B chunk at
// logical col-chunk cb lives at physical chunk (cb ^ (r&7)); applied on the
// staging side (per-lane gmem source; LDS dest lane-pinned), proven
// 0-conflict.
//
// EPI_PV: blockIdx.z = khalf*2 + batch; k-range [khalf*K, khalf*K+K);
//         C = c_f32 + khalf*chalf + batch*zC (plain f32 partial stores).
// Other EPIs: blockIdx.z = batch (offsets zA/zB/zC).
template <int EPI>
__global__ __launch_bounds__(256) void gemm128(
    const _Float16* __restrict__ A, int lda, size_t zA,
    const _Float16* __restrict__ Bt, int ldb, size_t zB,
    int K,
    float* __restrict__ c_f32,
    _Float16* __restrict__ c_f16,
    int ldc, size_t zC, size_t chalf,
    const float* __restrict__ bias,
    _Float16* __restrict__ q_out,
    _Float16* __restrict__ k_out,
    _Float16* __restrict__ v_out) {
  // 128*64 = 8192 elems (16 KB) + 3072-elem (6 KB) occupancy pad each.
  __shared__ __align__(16) _Float16 As[128 * 64 + 3072];
  __shared__ __align__(16) _Float16 Bs[128 * 64 + 3072];

  const int tid = threadIdx.x;
  const int wid = tid >> 6, lane = tid & 63;
  const int wr = wid >> 1, wc = wid & 1;       // wave grid 2x2 (64x64 each)
  const int lq = lane >> 4, lr = lane & 15;    // quad, row-in-tile
  const int m0 = blockIdx.x * 128, n0 = blockIdx.y * 128;
  const int z = blockIdx.z;
  int bidx, koff;
  if constexpr (EPI == EPI_PV) {
    bidx = z & 1;            // batch within chunk
    koff = (z >> 1) * K;     // k-half offset
  } else {
    bidx = z;
    koff = 0;
  }

  const _Float16* Ab = A + (size_t)bidx * zA + (size_t)m0 * lda + koff;
  const _Float16* Bb = Bt + (size_t)bidx * zB + (size_t)n0 * ldb + koff;

  v4f acc[4][4] = {};

  for (int k0 = 0; k0 < K; k0 += 64) {
    // Stage 16KB A + 16KB B: 1024 chunks of 16B each, 4 per thread per matrix.
    // chunk c: row r=c>>3; LDS physical chunk position c&7 holds logical
    // (gmem) col-chunk (c&7)^(r&7).
#pragma unroll
    for (int i = 0; i < 4; ++i) {
      const int c = i * 256 + tid;
      const int r = c >> 3;
      const int kc = (c & 7) ^ (r & 7);
      async_copy16(As + (size_t)c * 8, Ab + (size_t)r * lda + (k0 + kc * 8));
      async_copy16(Bs + (size_t)c * 8, Bb + (size_t)r * ldb + (k0 + kc * 8));
    }
    __syncthreads();

#pragma unroll
    for (int ks = 0; ks < 2; ++ks) {
      v8h af[4], bf[4];
#pragma unroll
      for (int t = 0; t < 4; ++t) {
        const int ra = wr * 64 + t * 16 + lr;
        const int rb = wc * 64 + t * 16 + lr;
        const int cb = ks * 4 + lq;
        af[t] = *(const v8h*)(As + ra * 64 + (((cb ^ (ra & 7)) << 3)));
        bf[t] = *(const v8h*)(Bs + rb * 64 + (((cb ^ (rb & 7)) << 3)));
      }
#pragma unroll
      for (int mt = 0; mt < 4; ++mt)
#pragma unroll
        for (int nt = 0; nt < 4; ++nt)
          acc[mt][nt] = __builtin_amdgcn_mfma_f32_16x16x32_f16(
              af[mt], bf[nt], acc[mt][nt], 0, 0, 0);
    }
    __syncthreads();
  }

  // Epilogue. C/D frag: col = lane&15, row = (lane>>4)*4 + reg (m89/m91).
  float* cf = nullptr;
  _Float16* ch = nullptr;
  if constexpr (EPI == EPI_PV)
    cf = c_f32 + (size_t)(z >> 1) * chalf + (size_t)bidx * zC;
  else if constexpr (EPI == EPI_OUT)
    cf = c_f32 + (size_t)bidx * zC;
  else if constexpr (EPI == EPI_F16)
    ch = c_f16 + (size_t)bidx * zC;

#pragma unroll
  for (int mt = 0; mt < 4; ++mt) {
#pragma unroll
    for (int nt = 0; nt < 4; ++nt) {
#pragma unroll
      for (int rg = 0; rg < 4; ++rg) {
        const int gm = m0 + wr * 64 + mt * 16 + lq * 4 + rg;
        const int gn = n0 + wc * 64 + nt * 16 + lr;
        float v = acc[mt][nt][rg];
        if constexpr (EPI == EPI_QKV) {
          v += bias[gn];
          if (gn < DD) {            // block-uniform branches (multiples of 128)
            q_out[(size_t)gm * DD + gn] = (_Float16)(v * ATT_SCALE);
          } else if (gn < 2 * DD) {
            k_out[(size_t)gm * DD + (gn - DD)] = (_Float16)v;
          } else {
            v_out[(size_t)gm * DD + (gn - 2 * DD)] = (_Float16)v;
          }
        } else if constexpr (EPI == EPI_F16) {
          ch[(size_t)gm * ldc + gn] = (_Float16)v;
        } else {  // EPI_PV / EPI_OUT
          cf[(size_t)gm * ldc + gn] = (EPI == EPI_OUT) ? v + bias[gn] : v;
        }
      }
    }
  }
}

// ---------------------------------------------------------------------------
// gemm256: R2's 4-phase counted-vmcnt kernel (best measured 256² structure).
// 256x256 tile, BK=64, 512 threads = 8 waves (2x4), per-wave 128x64 output.
// Used ONLY for QK^T: grid 16x16x2 = 512 blocks = exactly 2.0 rounds at
// 1 block/CU (128 KB LDS) -> no quantization tail.
// SWZ=1 (requires gx==16, gy==16): XCD x owns an 8x4 block supertile.
template <int EPI, int SWZ = 0>
__global__ __launch_bounds__(512, 2) void gemm256(
    const _Float16* __restrict__ A, int lda, size_t zA,
    const _Float16* __restrict__ Bt, int ldb, size_t zB,
    int K,
    float* __restrict__ c_f32,
    _Float16* __restrict__ c_f16,
    int ldc, size_t zC, size_t chalf,
    const float* __restrict__ bias,
    _Float16* __restrict__ q_out,
    _Float16* __restrict__ k_out,
    _Float16* __restrict__ v_out) {
  __shared__ __align__(16) _Float16 As[2][2][256 * 32];
  __shared__ __align__(16) _Float16 Bs[2][2][256 * 32];

  const int tid = threadIdx.x;
  const int wid = tid >> 6, lane = tid & 63;
  const int wr = wid >> 2, wc = wid & 3;       // wave grid 2x4 (128x64 each)
  const int lq = lane >> 4, lr = lane & 15;    // quad, row-in-tile

  int bx = blockIdx.x, by = blockIdx.y;
  if constexpr (SWZ == 1) {
    // Valid for gx=16, gy=16: bijective (xcd,j) -> 8x4 supertile coords.
    const int lin = bx + (by << 4);
    const int xcd = lin & 7, j = lin >> 3;  // j in [0,32)
    bx = (xcd & 1) * 8 + (j & 7);
    by = (xcd >> 1) * 4 + (j >> 3);
  }
  const int m0 = bx * 256, n0 = by * 256;
  const int z = blockIdx.z;
  int bidx, koff;
  if constexpr (EPI == EPI_PV) {
    bidx = z & 1;
    koff = (z >> 1) * K;
  } else {
    bidx = z;
    koff = 0;
  }

  const _Float16* Ab = A + (size_t)bidx * zA + (size_t)m0 * lda + koff;
  const _Float16* Bb = Bt + (size_t)bidx * zB + (size_t)n0 * ldb + koff;

  // Staging: per sub-tile 1024 16B-chunks, 2 per thread (c, c+512).
  // chunk c: r = c>>2, pc = c&3, logical kc = pc ^ ((r>>1)&3).
  const int c0 = tid, c1 = tid + 512;
  const int r0 = c0 >> 2, r1 = c1 >> 2;
  const int k0c = ((c0 & 3) ^ ((r0 >> 1) & 3)) << 3;  // logical col, elems
  const int k1c = ((c1 & 3) ^ ((r1 >> 1) & 3)) << 3;
  const size_t ga0 = (size_t)r0 * lda + k0c, ga1 = (size_t)r1 * lda + k1c;
  const size_t gb0 = (size_t)r0 * ldb + k0c, gb1 = (size_t)r1 * ldb + k1c;

  // Fragment read offsets (elems) within a 256x32 sub-tile.
  int aoff[8], boff[4];
#pragma unroll
  for (int t = 0; t < 8; ++t) {
    const int ra = wr * 128 + t * 16 + lr;
    aoff[t] = ra * 32 + ((lq ^ ((ra >> 1) & 3)) << 3);
  }
#pragma unroll
  for (int n = 0; n < 4; ++n) {
    const int rb = wc * 64 + n * 16 + lr;
    boff[n] = rb * 32 + ((lq ^ ((rb >> 1) & 3)) << 3);
  }

  v4f acc[8][4] = {};
  const int NT = K / 64;

  auto stageA = [&](int slot, int ks, int kt) {
    const _Float16* s = Ab + (size_t)(kt * 64 + ks * 32);
    async_copy16(&As[slot][ks][(size_t)c0 * 8], s + ga0);
    async_copy16(&As[slot][ks][(size_t)c1 * 8], s + ga1);
  };
  auto stageB = [&](int slot, int ks, int kt) {
    const _Float16* s = Bb + (size_t)(kt * 64 + ks * 32);
    async_copy16(&Bs[slot][ks][(size_t)c0 * 8], s + gb0);
    async_copy16(&Bs[slot][ks][(size_t)c1 * 8], s + gb1);
  };
  auto mfma16 = [&](const v8h* af_, const v8h* bf_, int mbase) {
#pragma unroll
    for (int mt = 0; mt < 4; ++mt)
#pragma unroll
      for (int nt = 0; nt < 4; ++nt)
        acc[mbase + mt][nt] = __builtin_amdgcn_mfma_f32_16x16x32_f16(
            af_[mt], bf_[nt], acc[mbase + mt][nt], 0, 0, 0);
  };

  // Prologue: tile 0 fully staged in consumption order (8 loads/thread).
  stageA(0, 0, 0);
  stageB(0, 0, 0);
  stageA(0, 1, 0);
  stageB(0, 1, 0);

  for (int t = 0; t < NT; ++t) {
    const int slot = t & 1, ns = slot ^ 1;
    const bool pre = (t + 1 < NT);
    const _Float16* A0s = &As[slot][0][0];
    const _Float16* B0s = &Bs[slot][0][0];
    const _Float16* A1s = &As[slot][1][0];
    const _Float16* B1s = &Bs[slot][1][0];

    v8h a_[4], b0_[4], b1_[4];

    // ---- phase 0: ks0, mt 0-3 ----
    if (pre) {
      stageA(ns, 0, t + 1);
      VM_WAIT(6);
    } else {
      VM_WAIT(4);
    }
    SCHED0;
    BAR;
    SCHED0;
#pragma unroll
    for (int i = 0; i < 4; ++i) a_[i] = *(const v8h*)(A0s + aoff[i]);
#pragma unroll
    for (int i = 0; i < 4; ++i) b0_[i] = *(const v8h*)(B0s + boff[i]);
    __builtin_amdgcn_s_setprio(1);
    mfma16(a_, b0_, 0);
    __builtin_amdgcn_s_setprio(0);

    // ---- phase 1: ks0, mt 4-7 (B ks0 regs still live) ----
    if (pre) stageB(ns, 0, t + 1);
#pragma unroll
    for (int i = 0; i < 4; ++i) a_[i] = *(const v8h*)(A0s + aoff[4 + i]);
    __builtin_amdgcn_s_setprio(1);
    mfma16(a_, b0_, 4);
    __builtin_amdgcn_s_setprio(0);

    // ---- phase 2: ks1, mt 0-3 ----
    if (pre) {
      stageA(ns, 1, t + 1);
      VM_WAIT(6);
    } else {
      VM_WAIT(0);
    }
    SCHED0;
    BAR;
    SCHED0;
#pragma unroll
    for (int i = 0; i < 4; ++i) a_[i] = *(const v8h*)(A1s + aoff[i]);
#pragma unroll
    for (int i = 0; i < 4; ++i) b1_[i] = *(const v8h*)(B1s + boff[i]);
    __builtin_amdgcn_s_setprio(1);
    mfma16(a_, b1_, 0);
    __builtin_amdgcn_s_setprio(0);

    // ---- phase 3: ks1, mt 4-7 ----
    if (pre) stageB(ns, 1, t + 1);
#pragma unroll
    for (int i = 0; i < 4; ++i) a_[i] = *(const v8h*)(A1s + aoff[4 + i]);
    __builtin_amdgcn_s_setprio(1);
    mfma16(a_, b1_, 4);
    __builtin_amdgcn_s_setprio(0);

    // Tile boundary: ds_reads drained before any wave stages over this slot.
    LGKM0;
    SCHED0;
    BAR;
    SCHED0;
  }

  // Epilogue.
  float* cf = nullptr;
  _Float16* ch = nullptr;
  if constexpr (EPI == EPI_PV)
    cf = c_f32 + (size_t)(z >> 1) * chalf + (size_t)bidx * zC;
  else if constexpr (EPI == EPI_OUT)
    cf = c_f32 + (size_t)bidx * zC;
  else if constexpr (EPI == EPI_F16)
    ch = c_f16 + (size_t)bidx * zC;

#pragma unroll
  for (int mt = 0; mt < 8; ++mt) {
#pragma unroll
    for (int nt = 0; nt < 4; ++nt) {
#pragma unroll
      for (int rg = 0; rg < 4; ++rg) {
        const int gm = m0 + wr * 128 + mt * 16 + lq * 4 + rg;
        const int gn = n0 + wc * 64 + nt * 16 + lr;
        float v = acc[mt][nt][rg];
        if constexpr (EPI == EPI_QKV) {
          v += bias[gn];
          if (gn < DD) {
            q_out[(size_t)gm * DD + gn] = (_Float16)(v * ATT_SCALE);
          } else if (gn < 2 * DD) {
            k_out[(size_t)gm * DD + (gn - DD)] = (_Float16)v;
          } else {
            v_out[(size_t)gm * DD + (gn - 2 * DD)] = (_Float16)v;
          }
        } else if constexpr (EPI == EPI_F16) {
          ch[(size_t)gm * ldc + gn] = (_Float16)v;
        } else {
          cf[(size_t)gm * ldc + gn] = (EPI == EPI_OUT) ? v + bias[gn] : v;
        }
      }
    }
  }
}

// ctx f16 = half0 + half1 (split-K reduce + f32->f16 convert).
__global__ __launch_bounds__(256) void reduce_ctx(const float* __restrict__ h0,
                                                  const float* __restrict__ h1,
                                                  _Float16* __restrict__ out,
                                                  int n4) {
  int i = blockIdx.x * blockDim.x + threadIdx.x;
  if (i < n4) {
    v4f a = ((const v4f*)h0)[i];
    v4f b = ((const v4f*)h1)[i];
    v4h o;
#pragma unroll
    for (int j = 0; j < 4; ++j) o[j] = (_Float16)(a[j] + b[j]);
    ((v4h*)out)[i] = o;
  }
}

// Row softmax over f16 scores, in place. Grid (NN, nz); one block per row.
__global__ __launch_bounds__(256) void softmax_rows_f16(_Float16* __restrict__ S) {
  _Float16* row = S + (size_t)blockIdx.y * NN * NN + (size_t)blockIdx.x * NN;
  const int tid = threadIdx.x;
  const int lane = tid & 63, wid = tid >> 6;

  float f[16];
  float m = -3.0e38f;
#pragma unroll
  for (int i = 0; i < 2; ++i) {
    v8h v = ((const v8h*)row)[tid + i * 256];
#pragma unroll
    for (int j = 0; j < 8; ++j) {
      f[i * 8 + j] = (float)v[j];
      m = fmaxf(m, f[i * 8 + j]);
    }
  }
#pragma unroll
  for (int off = 32; off > 0; off >>= 1) m = fmaxf(m, __shfl_xor(m, off));
  __shared__ float redm[4], reds[4];
  if (lane == 0) redm[wid] = m;
  __syncthreads();
  m = fmaxf(fmaxf(redm[0], redm[1]), fmaxf(redm[2], redm[3]));

  float sum = 0.f;
#pragma unroll
  for (int i = 0; i < 16; ++i) {
    f[i] = __expf(f[i] - m);
    sum += f[i];
  }
#pragma unroll
  for (int off = 32; off > 0; off >>= 1) sum += __shfl_xor(sum, off);
  if (lane == 0) reds[wid] = sum;
  __syncthreads();
  sum = reds[0] + reds[1] + reds[2] + reds[3];
  const float inv = 1.0f / sum;
#pragma unroll
  for (int i = 0; i < 2; ++i) {
    v8h o;
#pragma unroll
    for (int j = 0; j < 8; ++j) o[j] = (_Float16)(f[i * 8 + j] * inv);
    ((v8h*)row)[tid + i * 256] = o;
  }
}

__global__ __launch_bounds__(256) void cvt_f16(const float* __restrict__ in,
                                               _Float16* __restrict__ out, int n4) {
  int i = blockIdx.x * blockDim.x + threadIdx.x;
  if (i < n4) {
    v4f v = ((const v4f*)in)[i];
    v4h o;
#pragma unroll
    for (int j = 0; j < 4; ++j) o[j] = (_Float16)v[j];
    ((v4h*)out)[i] = o;
  }
}

// out[C][R] (f16) = in[R][C] (f32). Grid (C/32, R/32), 256 threads (32x8).
__global__ __launch_bounds__(256) void transpose_cvt(const float* __restrict__ in,
                                                     _Float16* __restrict__ out,
                                                     int R, int C) {
  __shared__ float tile[32][33];
  const int bx = blockIdx.x * 32;  // C base
  const int by = blockIdx.y * 32;  // R base
  const int tx = threadIdx.x & 31, ty = threadIdx.x >> 5;
#pragma unroll
  for (int i = 0; i < 32; i += 8)
    tile[ty + i][tx] = in[(size_t)(by + ty + i) * C + (bx + tx)];
  __syncthreads();
#pragma unroll
  for (int i = 0; i < 32; i += 8)
    out[(size_t)(bx + ty + i) * R + (by + tx)] = (_Float16)tile[tx][ty + i];
}

// Vt[b][d][n] = V[b][n][d], f16. Grid (DD/32, NN/32, BB).
__global__ __launch_bounds__(256) void transpose_v(const _Float16* __restrict__ in,
                                                   _Float16* __restrict__ out) {
  __shared__ _Float16 tile[32][33];
  const int b = blockIdx.z;
  const _Float16* src = in + (size_t)b * NN * DD;
  _Float16* dst = out + (size_t)b * NN * DD;
  const int bx = blockIdx.x * 32;  // DD base
  const int by = blockIdx.y * 32;  // NN base
  const int tx = threadIdx.x & 31, ty = threadIdx.x >> 5;
#pragma unroll
  for (int i = 0; i < 32; i += 8)
    tile[ty + i][tx] = src[(size_t)(by + ty + i) * DD + (bx + tx)];
  __syncthreads();
#pragma unroll
  for (int i = 0; i < 32; i += 8)
    dst[(size_t)(bx + ty + i) * NN + (by + tx)] = tile[tx][ty + i];
}

extern "C" void kernel_launch(void* const* d_in, const int* in_sizes, int n_in,
                              void* d_out, int out_size, void* d_ws, size_t ws_size,
                              hipStream_t stream) {
  const float* x = (const float*)d_in[0];      // [16384][768]
  const float* w_qkv = (const float*)d_in[1];  // [768][2304]
  const float* b_qkv = (const float*)d_in[2];  // [2304]
  const float* w_out = (const float*)d_in[3];  // [768][768]
  const float* b_out = (const float*)d_in[4];  // [768]
  float* out = (float*)d_out;                  // [16384][768] — also used as
                                               // split-K f32 partial scratch
  char* ws = (char*)d_ws;

  // ws layout, peak 164.5 MB (proven in prior rounds):
  _Float16* xh    = (_Float16*)(ws + 0);           // 25 MB  (dead after QKV gemm)
  _Float16* wqkvh = (_Float16*)(ws + 25165824);    // 3.5 MB [2304][768] = W^T
  _Float16* wouth = (_Float16*)(ws + 28704768);    // 1.2 MB [768][768]  = Wout^T
  _Float16* Qh    = (_Float16*)(ws + 29884416);    // 25 MB  (pre-scaled)
  _Float16* Kh    = (_Float16*)(ws + 55050240);    // 25 MB
  _Float16* Vh    = (_Float16*)(ws + 80216064);    // 25 MB  (dead after transpose)
  _Float16* Sh    = (_Float16*)(ws + 105381888);   // 64 MB  f16 scores, 2 batches
  _Float16* Vth   = (_Float16*)(ws + 0);           // reuse xh: [4][768][4096]
  _Float16* Ch    = (_Float16*)(ws + 80216064);    // reuse Vh: [16384][768] ctx

  const size_t zQK = (size_t)NN * DD;   // per-batch stride Q/K/Vt/C (f16 elems)
  const size_t zS = (size_t)NN * NN;    // per-batch stride S (f16 elems)
  const size_t zCtx = (size_t)NN * DD;  // per-batch stride ctx partial (f32)
  const size_t chalf = 2 * zCtx;        // k-half stride in d_out (f32 elems)

  // 1) precision converts / weight transposes
  cvt_f16<<<dim3((MTOT * DD / 4) / 256), 256, 0, stream>>>(x, xh, MTOT * DD / 4);
  transpose_cvt<<<dim3(EE / 32, DD / 32), 256, 0, stream>>>(w_qkv, wqkvh, DD, EE);
  transpose_cvt<<<dim3(DD / 32, DD / 32), 256, 0, stream>>>(w_out, wouth, DD, DD);

  // 2) fused QKV projection: 128² tile, grid 128x18 = 2304 = 3.0 exact rounds
  gemm128<EPI_QKV><<<dim3(MTOT / 128, EE / 128), 256, 0, stream>>>(
      xh, DD, 0, wqkvh, DD, 0, DD, nullptr, nullptr, 0, 0, 0, b_qkv, Qh, Kh, Vh);

  // 3) V -> V^T for the PV gemm's n-major B operand
  transpose_v<<<dim3(DD / 32, NN / 32, BB), 256, 0, stream>>>(Vh, Vth);

  // 4) attention in 2-batch chunks: S=QK^T (256², 512 blocks = 2.0 rounds);
  //    softmax; ctx=PV split-K=2 (128², 768 blocks = 1.0 round, K=2048).
  for (int c = 0; c < BB / 2; ++c) {
    const _Float16* Qc = Qh + (size_t)c * 2 * zQK;
    const _Float16* Kc = Kh + (size_t)c * 2 * zQK;
    const _Float16* Vtc = Vth + (size_t)c * 2 * zQK;
    gemm256<EPI_F16, 1><<<dim3(NN / 256, NN / 256, 2), 512, 0, stream>>>(
        Qc, DD, zQK, Kc, DD, zQK, DD, nullptr, Sh, NN, zS, 0, nullptr, nullptr,
        nullptr, nullptr);
    softmax_rows_f16<<<dim3(NN, 2), 256, 0, stream>>>(Sh);
    gemm128<EPI_PV><<<dim3(NN / 128, DD / 128, 4), 256, 0, stream>>>(
        Sh, NN, zS, Vtc, NN, zQK, NN / 2, out, nullptr, DD, zCtx, chalf,
        nullptr, nullptr, nullptr, nullptr);
    reduce_ctx<<<dim3((int)(chalf / 4 / 256)), 256, 0, stream>>>(
        out, out + chalf, Ch + (size_t)c * 2 * zQK, (int)(chalf / 4));
  }

  // 5) output projection: 128² tile, grid 128x6 = 768 = 1.0 exact round
  gemm128<EPI_OUT><<<dim3(MTOT / 128, DD / 128), 256, 0, stream>>>(
      Ch, DD, 0, wouth, DD, 0, DD, out, nullptr, DD, 0, 0, b_out, nullptr,
      nullptr, nullptr);
}

// Round 5
// 525.096 us; speedup vs baseline: 1.1034x; 1.1034x over previous
//
#include <hip/hip_runtime.h>
#include <cstdint>
#include <cstddef>

#define BB 4
#define NN 4096
#define DD 768
#define EE 2304      // 3*DD
#define MTOT 16384   // BB*NN
static constexpr float ATT_SCALE = 0.03608439182435161f;  // 1/sqrt(768)

typedef _Float16 v8h __attribute__((ext_vector_type(8)));
typedef _Float16 v4h __attribute__((ext_vector_type(4)));
typedef float v4f __attribute__((ext_vector_type(4)));
typedef uint32_t v4u __attribute__((ext_vector_type(4)));

#define LGKM0 asm volatile("s_waitcnt lgkmcnt(0)" ::: "memory")
#define SCHED0 __builtin_amdgcn_sched_barrier(0)
#define BAR __builtin_amdgcn_s_barrier()

enum { EPI_QKV = 0, EPI_F16 = 1, EPI_OUT = 2, EPI_PV = 3 };

// C[M,N] = A[M,K] @ Bt[N,K]^T.  A row-major (lda), Bt n-major (ldb).
// 256x256 tile, BK=64, 512 threads = 8 waves (2x4), per-wave 128x64 output.
//
// ROUND-5 CHANGE (single variable vs R2-best): staging mechanism is
// REGISTER-STAGED, not global_load_lds DMA.  Per K-tile per thread:
//   8 x global_load_dwordx4 -> 32 VGPRs  (issued at END of iter t for tile
//   t+2: ~1 full K-tile of latency slack; compiler's automatic counted
//   vmcnt before first register use never drains to 0 mid-loop)
//   8 x ds_write_b128 into slot ns       (after ALL of tile t's ds_reads,
//   so no LDS may-alias stall; lgkmcnt(0)+barrier publishes before t+1)
// Everything else (4-phase MFMA order, grids, epilogues) identical to R2.
// This is the pre-committed A/B: flat result => DMA path was not binding.
//
// LDS: 2 slots x {A,B} x [256 rows][64 elems] (32 KB each) = 128 KB.
// Swizzle (proven 0-conflict read pattern): row r, physical 16B-chunk
// pc = kc ^ (r&7) — now applied on the ds_write ADDRESS (we control the
// write side with reg-staging).  ks1 fragment offsets = ks0 offsets ^ 32
// elems (chunk bit2 flip; row term has only bits >=6, so XOR is exact).
//
// SWZ=1 (QK^T only; requires gx==16, gy==16): XCD x owns an 8x4 block
// supertile -> co-resident L2 working set ~4.7 MB.
//
// EPI_PV: blockIdx.z = khalf*2 + batch; k-range [khalf*K, khalf*K+K);
//         C = c_f32 + khalf*chalf + batch*zC (plain f32 partial stores).
// Other EPIs: blockIdx.z = batch (offsets zA/zB/zC).
template <int EPI, int SWZ = 0>
__global__ __launch_bounds__(512, 2) void gemm256(
    const _Float16* __restrict__ A, int lda, size_t zA,
    const _Float16* __restrict__ Bt, int ldb, size_t zB,
    int K,
    float* __restrict__ c_f32,
    _Float16* __restrict__ c_f16,
    int ldc, size_t zC, size_t chalf,
    const float* __restrict__ bias,
    _Float16* __restrict__ q_out,
    _Float16* __restrict__ k_out,
    _Float16* __restrict__ v_out) {
  __shared__ __align__(16) _Float16 As[2][256 * 64];
  __shared__ __align__(16) _Float16 Bs[2][256 * 64];

  const int tid = threadIdx.x;
  const int wid = tid >> 6, lane = tid & 63;
  const int wr = wid >> 2, wc = wid & 3;       // wave grid 2x4 (128x64 each)
  const int lq = lane >> 4, lr = lane & 15;    // quad, row-in-tile

  int bx = blockIdx.x, by = blockIdx.y;
  if constexpr (SWZ == 1) {
    // Valid for gx=16, gy=16: bijective (xcd,j) -> 8x4 supertile coords.
    const int lin = bx + (by << 4);
    const int xcd = lin & 7, j = lin >> 3;  // j in [0,32)
    bx = (xcd & 1) * 8 + (j & 7);
    by = (xcd >> 1) * 4 + (j >> 3);
  }
  const int m0 = bx * 256, n0 = by * 256;
  const int z = blockIdx.z;
  int bidx, koff;
  if constexpr (EPI == EPI_PV) {
    bidx = z & 1;            // batch within chunk
    koff = (z >> 1) * K;     // k-half offset
  } else {
    bidx = z;
    koff = 0;
  }

  const _Float16* Ab = A + (size_t)bidx * zA + (size_t)m0 * lda + koff;
  const _Float16* Bb = Bt + (size_t)bidx * zB + (size_t)n0 * ldb + koff;

  // Staging map: 2048 16B-chunks per matrix per K-tile, 4 per thread.
  // chunk c = i*512+tid: row r = c>>3, logical k-chunk kc = c&7.
  // gmem: linear (r, kc); LDS: physical chunk pc = kc ^ (r&7).
  int gA[4], gB[4], lds_off[4];
#pragma unroll
  for (int i = 0; i < 4; ++i) {
    const int c = i * 512 + tid;
    const int r = c >> 3, kc = c & 7;
    gA[i] = r * lda + kc * 8;
    gB[i] = r * ldb + kc * 8;
    lds_off[i] = r * 64 + ((kc ^ (r & 7)) << 3);
  }

  // Fragment read offsets (elems), ks=0; ks=1 is ^32.
  int aoff[8], boff[4];
#pragma unroll
  for (int t = 0; t < 8; ++t) {
    const int ra = wr * 128 + t * 16 + lr;
    aoff[t] = ra * 64 + ((lq ^ (ra & 7)) << 3);
  }
#pragma unroll
  for (int n = 0; n < 4; ++n) {
    const int rb = wc * 64 + n * 16 + lr;
    boff[n] = rb * 64 + ((lq ^ (rb & 7)) << 3);
  }

  v4f acc[8][4] = {};
  const int NT = K / 64;  // all call sites: NT >= 6

  v4u va[4], vb[4];  // in-flight staging registers (32 VGPR)

  auto loadT = [&](int kt) {
    const _Float16* a = Ab + kt * 64;
    const _Float16* b = Bb + kt * 64;
#pragma unroll
    for (int i = 0; i < 4; ++i) {
      va[i] = *(const v4u*)(a + gA[i]);
      vb[i] = *(const v4u*)(b + gB[i]);
    }
  };
  auto writeT = [&](int slot) {
#pragma unroll
    for (int i = 0; i < 4; ++i) {
      *(v4u*)(&As[slot][0] + lds_off[i]) = va[i];
      *(v4u*)(&Bs[slot][0] + lds_off[i]) = vb[i];
    }
  };
  auto mfma16 = [&](const v8h* af_, const v8h* bf_, int mbase) {
#pragma unroll
    for (int mt = 0; mt < 4; ++mt)
#pragma unroll
      for (int nt = 0; nt < 4; ++nt)
        acc[mbase + mt][nt] = __builtin_amdgcn_mfma_f32_16x16x32_f16(
            af_[mt], bf_[nt], acc[mbase + mt][nt], 0, 0, 0);
  };

  // Prologue: tile 0 -> regs -> slot 0; issue tile 1 loads; publish.
  loadT(0);
  writeT(0);
  loadT(1);
  LGKM0;
  SCHED0;
  BAR;
  SCHED0;

  for (int t = 0; t < NT; ++t) {
    const int cur = t & 1, ns = cur ^ 1;
    const _Float16* Ac = &As[cur][0];
    const _Float16* Bc = &Bs[cur][0];
    v8h a_[4], b0_[4], b1_[4];

    // ---- phase 0: ks0, mt 0-3 ----
#pragma unroll
    for (int i = 0; i < 4; ++i) a_[i] = *(const v8h*)(Ac + aoff[i]);
#pragma unroll
    for (int i = 0; i < 4; ++i) b0_[i] = *(const v8h*)(Bc + boff[i]);
    __builtin_amdgcn_s_setprio(1);
    mfma16(a_, b0_, 0);
    __builtin_amdgcn_s_setprio(0);

    // ---- phase 1: ks0, mt 4-7 (b0_ live) ----
#pragma unroll
    for (int i = 0; i < 4; ++i) a_[i] = *(const v8h*)(Ac + aoff[4 + i]);
    __builtin_amdgcn_s_setprio(1);
    mfma16(a_, b0_, 4);
    __builtin_amdgcn_s_setprio(0);

    // ---- phase 2: ks1, mt 0-3 ----
#pragma unroll
    for (int i = 0; i < 4; ++i) a_[i] = *(const v8h*)(Ac + (aoff[i] ^ 32));
#pragma unroll
    for (int i = 0; i < 4; ++i) b1_[i] = *(const v8h*)(Bc + (boff[i] ^ 32));
    __builtin_amdgcn_s_setprio(1);
    mfma16(a_, b1_, 0);
    __builtin_amdgcn_s_setprio(0);

    // ---- phase 3: ks1, mt 4-7 ----
#pragma unroll
    for (int i = 0; i < 4; ++i) a_[i] = *(const v8h*)(Ac + (aoff[4 + i] ^ 32));
    __builtin_amdgcn_s_setprio(1);
    mfma16(a_, b1_, 4);
    __builtin_amdgcn_s_setprio(0);

    // ---- stage tail: all reads of slot cur are done above ----
    if (t + 1 < NT) {
      writeT(ns);                    // regs (tile t+1) -> LDS; compiler's
      if (t + 2 < NT) loadT(t + 2);  // counted vmcnt; then reissue loads
    }
    LGKM0;   // ds_writes + ds_reads drained before any wave crosses
    SCHED0;
    BAR;
    SCHED0;
  }

  // Epilogue. C/D frag: col = lane&15, row = (lane>>4)*4 + reg (m89/m91).
  float* cf = nullptr;
  _Float16* ch = nullptr;
  if constexpr (EPI == EPI_PV)
    cf = c_f32 + (size_t)(z >> 1) * chalf + (size_t)bidx * zC;
  else if constexpr (EPI == EPI_OUT)
    cf = c_f32 + (size_t)bidx * zC;
  else if constexpr (EPI == EPI_F16)
    ch = c_f16 + (size_t)bidx * zC;

#pragma unroll
  for (int mt = 0; mt < 8; ++mt) {
#pragma unroll
    for (int nt = 0; nt < 4; ++nt) {
#pragma unroll
      for (int rg = 0; rg < 4; ++rg) {
        const int gm = m0 + wr * 128 + mt * 16 + lq * 4 + rg;
        const int gn = n0 + wc * 64 + nt * 16 + lr;
        float v = acc[mt][nt][rg];
        if constexpr (EPI == EPI_QKV) {
          v += bias[gn];
          if (gn < DD) {            // uniform per 16-wide run (768 % 16 == 0)
            q_out[(size_t)gm * DD + gn] = (_Float16)(v * ATT_SCALE);
          } else if (gn < 2 * DD) {
            k_out[(size_t)gm * DD + (gn - DD)] = (_Float16)v;
          } else {
            v_out[(size_t)gm * DD + (gn - 2 * DD)] = (_Float16)v;
          }
        } else if constexpr (EPI == EPI_F16) {
          ch[(size_t)gm * ldc + gn] = (_Float16)v;
        } else {  // EPI_PV / EPI_OUT
          cf[(size_t)gm * ldc + gn] = (EPI == EPI_OUT) ? v + bias[gn] : v;
        }
      }
    }
  }
}

// ctx f16 = half0 + half1 (split-K reduce + f32->f16 convert).
__global__ __launch_bounds__(256) void reduce_ctx(const float* __restrict__ h0,
                                                  const float* __restrict__ h1,
                                                  _Float16* __restrict__ out,
                                                  int n4) {
  int i = blockIdx.x * blockDim.x + threadIdx.x;
  if (i < n4) {
    v4f a = ((const v4f*)h0)[i];
    v4f b = ((const v4f*)h1)[i];
    v4h o;
#pragma unroll
    for (int j = 0; j < 4; ++j) o[j] = (_Float16)(a[j] + b[j]);
    ((v4h*)out)[i] = o;
  }
}

// Row softmax over f16 scores, in place. Grid (NN, nz); one block per row.
__global__ __launch_bounds__(256) void softmax_rows_f16(_Float16* __restrict__ S) {
  _Float16* row = S + (size_t)blockIdx.y * NN * NN + (size_t)blockIdx.x * NN;
  const int tid = threadIdx.x;
  const int lane = tid & 63, wid = tid >> 6;

  float f[16];
  float m = -3.0e38f;
#pragma unroll
  for (int i = 0; i < 2; ++i) {
    v8h v = ((const v8h*)row)[tid + i * 256];
#pragma unroll
    for (int j = 0; j < 8; ++j) {
      f[i * 8 + j] = (float)v[j];
      m = fmaxf(m, f[i * 8 + j]);
    }
  }
#pragma unroll
  for (int off = 32; off > 0; off >>= 1) m = fmaxf(m, __shfl_xor(m, off));
  __shared__ float redm[4], reds[4];
  if (lane == 0) redm[wid] = m;
  __syncthreads();
  m = fmaxf(fmaxf(redm[0], redm[1]), fmaxf(redm[2], redm[3]));

  float sum = 0.f;
#pragma unroll
  for (int i = 0; i < 16; ++i) {
    f[i] = __expf(f[i] - m);
    sum += f[i];
  }
#pragma unroll
  for (int off = 32; off > 0; off >>= 1) sum += __shfl_xor(sum, off);
  if (lane == 0) reds[wid] = sum;
  __syncthreads();
  sum = reds[0] + reds[1] + reds[2] + reds[3];
  const float inv = 1.0f / sum;
#pragma unroll
  for (int i = 0; i < 2; ++i) {
    v8h o;
#pragma unroll
    for (int j = 0; j < 8; ++j) o[j] = (_Float16)(f[i * 8 + j] * inv);
    ((v8h*)row)[tid + i * 256] = o;
  }
}

__global__ __launch_bounds__(256) void cvt_f16(const float* __restrict__ in,
                                               _Float16* __restrict__ out, int n4) {
  int i = blockIdx.x * blockDim.x + threadIdx.x;
  if (i < n4) {
    v4f v = ((const v4f*)in)[i];
    v4h o;
#pragma unroll
    for (int j = 0; j < 4; ++j) o[j] = (_Float16)v[j];
    ((v4h*)out)[i] = o;
  }
}

// out[C][R] (f16) = in[R][C] (f32). Grid (C/32, R/32), 256 threads (32x8).
__global__ __launch_bounds__(256) void transpose_cvt(const float* __restrict__ in,
                                                     _Float16* __restrict__ out,
                                                     int R, int C) {
  __shared__ float tile[32][33];
  const int bx = blockIdx.x * 32;  // C base
  const int by = blockIdx.y * 32;  // R base
  const int tx = threadIdx.x & 31, ty = threadIdx.x >> 5;
#pragma unroll
  for (int i = 0; i < 32; i += 8)
    tile[ty + i][tx] = in[(size_t)(by + ty + i) * C + (bx + tx)];
  __syncthreads();
#pragma unroll
  for (int i = 0; i < 32; i += 8)
    out[(size_t)(bx + ty + i) * R + (by + tx)] = (_Float16)tile[tx][ty + i];
}

// Vt[b][d][n] = V[b][n][d], f16. Grid (DD/32, NN/32, BB).
__global__ __launch_bounds__(256) void transpose_v(const _Float16* __restrict__ in,
                                                   _Float16* __restrict__ out) {
  __shared__ _Float16 tile[32][33];
  const int b = blockIdx.z;
  const _Float16* src = in + (size_t)b * NN * DD;
  _Float16* dst = out + (size_t)b * NN * DD;
  const int bx = blockIdx.x * 32;  // DD base
  const int by = blockIdx.y * 32;  // NN base
  const int tx = threadIdx.x & 31, ty = threadIdx.x >> 5;
#pragma unroll
  for (int i = 0; i < 32; i += 8)
    tile[ty + i][tx] = src[(size_t)(by + ty + i) * DD + (bx + tx)];
  __syncthreads();
#pragma unroll
  for (int i = 0; i < 32; i += 8)
    dst[(size_t)(bx + ty + i) * NN + (by + tx)] = tile[tx][ty + i];
}

extern "C" void kernel_launch(void* const* d_in, const int* in_sizes, int n_in,
                              void* d_out, int out_size, void* d_ws, size_t ws_size,
                              hipStream_t stream) {
  const float* x = (const float*)d_in[0];      // [16384][768]
  const float* w_qkv = (const float*)d_in[1];  // [768][2304]
  const float* b_qkv = (const float*)d_in[2];  // [2304]
  const float* w_out = (const float*)d_in[3];  // [768][768]
  const float* b_out = (const float*)d_in[4];  // [768]
  float* out = (float*)d_out;                  // [16384][768] — also used as
                                               // split-K f32 partial scratch
  char* ws = (char*)d_ws;

  // ws layout, peak 164.5 MB (proven in prior rounds):
  _Float16* xh    = (_Float16*)(ws + 0);           // 25 MB  (dead after QKV gemm)
  _Float16* wqkvh = (_Float16*)(ws + 25165824);    // 3.5 MB [2304][768] = W^T
  _Float16* wouth = (_Float16*)(ws + 28704768);    // 1.2 MB [768][768]  = Wout^T
  _Float16* Qh    = (_Float16*)(ws + 29884416);    // 25 MB  (pre-scaled)
  _Float16* Kh    = (_Float16*)(ws + 55050240);    // 25 MB
  _Float16* Vh    = (_Float16*)(ws + 80216064);    // 25 MB  (dead after transpose)
  _Float16* Sh    = (_Float16*)(ws + 105381888);   // 64 MB  f16 scores, 2 batches
  _Float16* Vth   = (_Float16*)(ws + 0);           // reuse xh: [4][768][4096]
  _Float16* Ch    = (_Float16*)(ws + 80216064);    // reuse Vh: [16384][768] ctx

  const size_t zQK = (size_t)NN * DD;   // per-batch stride Q/K/Vt/C (f16 elems)
  const size_t zS = (size_t)NN * NN;    // per-batch stride S (f16 elems)
  const size_t zCtx = (size_t)NN * DD;  // per-batch stride ctx partial (f32)
  const size_t chalf = 2 * zCtx;        // k-half stride in d_out (f32 elems)

  // 1) precision converts / weight transposes
  cvt_f16<<<dim3((MTOT * DD / 4) / 256), 256, 0, stream>>>(x, xh, MTOT * DD / 4);
  transpose_cvt<<<dim3(EE / 32, DD / 32), 256, 0, stream>>>(w_qkv, wqkvh, DD, EE);
  transpose_cvt<<<dim3(DD / 32, DD / 32), 256, 0, stream>>>(w_out, wouth, DD, DD);

  // 2) fused QKV projection (scale folded into Q): grid (64, 9)
  gemm256<EPI_QKV><<<dim3(MTOT / 256, EE / 256), 512, 0, stream>>>(
      xh, DD, 0, wqkvh, DD, 0, DD, nullptr, nullptr, 0, 0, 0, b_qkv, Qh, Kh, Vh);

  // 3) V -> V^T for the PV gemm's n-major B operand
  transpose_v<<<dim3(DD / 32, NN / 32, BB), 256, 0, stream>>>(Vh, Vth);

  // 4) attention in 2-batch chunks: S=QK^T (f16) ; softmax ; ctx=PV split-K=2
  //    PV partials: plain f32 stores into the two halves of d_out (50.3 MB =
  //    exactly 2 halves x 2 batches x 4096 x 768 f32), then reduce to Ch f16.
  for (int c = 0; c < BB / 2; ++c) {
    const _Float16* Qc = Qh + (size_t)c * 2 * zQK;
    const _Float16* Kc = Kh + (size_t)c * 2 * zQK;
    const _Float16* Vtc = Vth + (size_t)c * 2 * zQK;
    gemm256<EPI_F16, 1><<<dim3(NN / 256, NN / 256, 2), 512, 0, stream>>>(
        Qc, DD, zQK, Kc, DD, zQK, DD, nullptr, Sh, NN, zS, 0, nullptr, nullptr,
        nullptr, nullptr);
    softmax_rows_f16<<<dim3(NN, 2), 256, 0, stream>>>(Sh);
    gemm256<EPI_PV><<<dim3(NN / 256, DD / 256, 4), 512, 0, stream>>>(
        Sh, NN, zS, Vtc, NN, zQK, NN / 2, out, nullptr, DD, zCtx, chalf,
        nullptr, nullptr, nullptr, nullptr);
    reduce_ctx<<<dim3((int)(chalf / 4 / 256)), 256, 0, stream>>>(
        out, out + chalf, Ch + (size_t)c * 2 * zQK, (int)(chalf / 4));
  }

  // 5) output projection (reads Ch f16; overwrites d_out with final f32+bias)
  gemm256<EPI_OUT><<<dim3(MTOT / 256, DD / 256), 512, 0, stream>>>(
      Ch, DD, 0, wouth, DD, 0, DD, out, nullptr, DD, 0, 0, b_out, nullptr,
      nullptr, nullptr);
}